// Round 15
// baseline (1031.842 us; speedup 1.0000x reference)
//
#include <hip/hip_runtime.h>
#include <hip/hip_bf16.h>
#include <hip/hip_fp16.h>
#include <math.h>

#define NN 65536
#define NE 1048576
#define NB 64
#define HD 128
#define NL 3

// ---- workspace layout (float offsets) ----
#define O_CSUM   0
#define O_CCNT   192
#define O_LCNT   256
#define O_GSUM   320         // -> 8512
#define O_DEGI   8512        // -> 74048
#define O_POSREL 74048       // -> 270656
#define O_RC     270656      // -> 1319232
#define O_XHI    1319232     // NN*128 ushort -> 5513536
#define O_XLO    5513536     // -> 9707840
#define O_P      9707840     // NN*128 fp16 -> 18096448
#define O_Q      18096448    // -> 26485056
#define O_MSUM   26485056    // -> 34873664
#define O_W2T    34873664    // 3*128*128 fp16 -> 34898240
#define O_W1TH   34898240    // -> 34947392
#define O_W1TL   34947392    // -> 34996544
#define O_WUTH   34996544    // -> 35045696
#define O_WUTL   35045696    // -> 35094848
#define O_CHK    35094848    // 256 ints -> 35095104 (~140.4 MB)

typedef __attribute__((ext_vector_type(8))) short bf16x8;
typedef __attribute__((ext_vector_type(8))) _Float16 f16x8;
typedef __attribute__((ext_vector_type(8))) unsigned short u16x8;
typedef __attribute__((ext_vector_type(4))) float f32x4;

__device__ __forceinline__ void atomAdd(float* p, float v) { unsafeAtomicAdd(p, v); }

__device__ __forceinline__ unsigned short f2bf(float f) {
    union { __hip_bfloat16 h; unsigned short u; } cv;
    cv.h = __float2bfloat16(f);
    return cv.u;
}
__device__ __forceinline__ float bf2f(unsigned short u) {
    union { float f; unsigned v; } c; c.v = ((unsigned)u) << 16; return c.f;
}
__device__ __forceinline__ void split2(float v, unsigned short& h, unsigned short& l) {
    h = f2bf(v); l = f2bf(v - bf2f(h));
}
__device__ __forceinline__ unsigned short f2h(float f) {
    union { __half h; unsigned short u; } c; c.h = __float2half(f); return c.u;
}

// ---------------- stats ----------------
__global__ __launch_bounds__(256) void stats_kernel(
    const float* __restrict__ pos, const int* __restrict__ batch,
    const int* __restrict__ ntype,
    float* __restrict__ csum, float* __restrict__ ccnt, float* __restrict__ lcnt)
{
    __shared__ float s[NB * 5];
    const int tid = threadIdx.x;
    for (int i = tid; i < NB * 5; i += 256) s[i] = 0.f;
    __syncthreads();
    const int n = blockIdx.x * 256 + tid;
    const int b = batch[n];
    atomicAdd(&s[b*5+0], pos[n*3+0]);
    atomicAdd(&s[b*5+1], pos[n*3+1]);
    atomicAdd(&s[b*5+2], pos[n*3+2]);
    atomicAdd(&s[b*5+3], 1.f);
    if (ntype[n] == 1) atomicAdd(&s[b*5+4], 1.f);
    __syncthreads();
    for (int i = tid; i < NB * 5; i += 256) {
        float v = s[i];
        if (v != 0.f) {
            int b2 = i / 5, f = i - b2*5;
            if (f < 3)       atomAdd(&csum[b2*3+f], v);
            else if (f == 3) atomAdd(&ccnt[b2], v);
            else             atomAdd(&lcnt[b2], v);
        }
    }
}

// ---------------- degree histogram ----------------
__global__ __launch_bounds__(256) void deg_kernel(const int* __restrict__ row, int* __restrict__ degi)
{
    const int e = blockIdx.x * 256 + threadIdx.x;
    atomicAdd(&degi[row[e]], 1);
}

// ---------------- two-level scan ----------------
__global__ __launch_bounds__(256) void scanA_kernel(const int* __restrict__ degi, int* __restrict__ chunkSum)
{
    __shared__ int red[4];
    const int t = threadIdx.x, b = blockIdx.x;
    int v = degi[b*256 + t];
    #pragma unroll
    for (int off = 32; off > 0; off >>= 1) v += __shfl_down(v, off, 64);
    if ((t & 63) == 0) red[t >> 6] = v;
    __syncthreads();
    if (t == 0) chunkSum[b] = red[0] + red[1] + red[2] + red[3];
}

__global__ __launch_bounds__(256) void scanB_kernel(int* __restrict__ chunkSum)
{
    __shared__ int s[256];
    const int t = threadIdx.x;
    const int v = chunkSum[t];
    s[t] = v;
    __syncthreads();
    #pragma unroll
    for (int off = 1; off < 256; off <<= 1) {
        int u = (t >= off) ? s[t - off] : 0;
        __syncthreads();
        s[t] += u;
        __syncthreads();
    }
    chunkSum[t] = s[t] - v;   // exclusive
}

__global__ __launch_bounds__(256) void scanC_kernel(const int* __restrict__ degi,
                                                    const int* __restrict__ chunkOff,
                                                    int* __restrict__ rowStart)
{
    __shared__ int s[256];
    const int t = threadIdx.x, b = blockIdx.x;
    const int v = degi[b*256 + t];
    s[t] = v;
    __syncthreads();
    #pragma unroll
    for (int off = 1; off < 256; off <<= 1) {
        int u = (t >= off) ? s[t - off] : 0;
        __syncthreads();
        s[t] += u;
        __syncthreads();
    }
    rowStart[b*256 + t] = chunkOff[b] + s[t] - v;
}

// ---------------- counting-sort scatter ----------------
__global__ __launch_bounds__(256) void scatter_kernel(
    const int* __restrict__ row, const int* __restrict__ col,
    const int* __restrict__ rowStart, int* __restrict__ cnt,
    unsigned int* __restrict__ rcS)
{
    const int e = blockIdx.x * 256 + threadIdx.x;
    const int r = row[e], c = col[e];
    const int p = rowStart[r] + atomicAdd(&cnt[r], 1);
    rcS[p] = ((unsigned)r << 16) | (unsigned)c;
}

// ---------------- pos_rel ----------------
__global__ __launch_bounds__(256) void posrel_kernel(
    const float* __restrict__ pos, const int* __restrict__ batch,
    const float* __restrict__ csum, const float* __restrict__ ccnt,
    float* __restrict__ posrel)
{
    const int n = blockIdx.x * 256 + threadIdx.x;
    const int b = batch[n];
    const float inv = 1.f / fmaxf(ccnt[b], 1.f);
    posrel[n*3+0] = pos[n*3+0] - csum[b*3+0]*inv;
    posrel[n*3+1] = pos[n*3+1] - csum[b*3+1]*inv;
    posrel[n*3+2] = pos[n*3+2] - csum[b*3+2]*inv;
}

// ---------------- weight prep (W2T fp16) ----------------
__global__ __launch_bounds__(256) void wprep_kernel(
    const float* __restrict__ mw1, const float* __restrict__ uw,
    const float* __restrict__ mw2,
    unsigned short* __restrict__ w1th, unsigned short* __restrict__ w1tl,
    unsigned short* __restrict__ wuth, unsigned short* __restrict__ wutl,
    unsigned short* __restrict__ w2t)
{
    const int idx = blockIdx.x * 256 + threadIdx.x;   // 98304
    {   // W1T: [l][c<256][k<128]
        const int l = idx >> 15, rem = idx & 32767, c = rem >> 7, k = rem & 127;
        const int kk = (c < 128) ? k : (128 + k);
        const int cc = c & 127;
        const float v = mw1[l*257*128 + kk*128 + cc];
        unsigned short h, lo; split2(v, h, lo);
        w1th[idx] = h; w1tl[idx] = lo;
    }
    {   // WuT: [l][c<128][k<256] = uw[l][k][c]
        const int l = idx >> 15, rem = idx & 32767, c = rem >> 8, k = rem & 255;
        const float v = uw[l*256*128 + k*128 + c];
        unsigned short h, lo; split2(v, h, lo);
        wuth[idx] = h; wutl[idx] = lo;
    }
    if (idx < 49152) {   // W2T fp16: [l][n][k] = mw2[l][k][n]
        const int l = idx >> 14, rem = idx & 16383, n = rem >> 7, k = rem & 127;
        w2t[idx] = f2h(mw2[(l << 14) + k*128 + n]);
    }
}

// ---------------- lin_in ----------------
__global__ __launch_bounds__(256) void lin_in_gemm(
    const float* __restrict__ emb, const float* __restrict__ posrel,
    const int* __restrict__ zidx,
    const float* __restrict__ W, const float* __restrict__ bias,
    unsigned short* __restrict__ xhi, unsigned short* __restrict__ xlo)
{
    __shared__ __align__(16) float Asm[32][132];
    __shared__ __align__(16) float Wsm[32][128];
    const int tid = threadIdx.x;
    const int n0  = blockIdx.x * 32;
    const float4* __restrict__ A0f4 = (const float4*)emb;

    for (int idx4 = tid; idx4 < 1024; idx4 += 256) {
        int i = idx4 >> 5, k4 = idx4 & 31;
        int zz = zidx[n0 + i];
        *(float4*)&Asm[i][k4*4] = A0f4[zz*32 + k4];
    }
    if (tid < 96) { int i = tid / 3, d = tid - i*3; Asm[i][128+d] = posrel[(n0+i)*3 + d]; }
    else if (tid < 128) { Asm[tid-96][131] = 0.f; }

    const int tj = tid & 31;
    const int tn = tid >> 5;
    float acc[4][4];
    #pragma unroll
    for (int r = 0; r < 4; ++r)
        #pragma unroll
        for (int c = 0; c < 4; ++c) acc[r][c] = 0.f;

    const float4* __restrict__ Wf4 = (const float4*)W;
    #pragma unroll 1
    for (int kc = 0; kc < 131; kc += 32) {
        const int kend = (131 - kc < 32) ? (131 - kc) : 32;
        __syncthreads();
        for (int idx4 = tid; idx4 < kend*32; idx4 += 256) {
            int kk = idx4 >> 5, j4 = idx4 & 31;
            *(float4*)&Wsm[kk][j4*4] = Wf4[(kc+kk)*32 + j4];
        }
        __syncthreads();
        for (int kk = 0; kk < kend; ++kk) {
            const float4 w = *(const float4*)&Wsm[kk][tj*4];
            #pragma unroll
            for (int r = 0; r < 4; ++r) {
                const float a = Asm[tn*4+r][kc+kk];
                acc[r][0] += a*w.x; acc[r][1] += a*w.y; acc[r][2] += a*w.z; acc[r][3] += a*w.w;
            }
        }
    }

    const float4 bias4 = ((const float4*)bias)[tj];
    #pragma unroll
    for (int r = 0; r < 4; ++r) {
        const int node = n0 + tn*4 + r;
        const float o[4] = { acc[r][0] + bias4.x, acc[r][1] + bias4.y,
                             acc[r][2] + bias4.z, acc[r][3] + bias4.w };
        ushort4 h4, l4;
        split2(o[0], h4.x, l4.x); split2(o[1], h4.y, l4.y);
        split2(o[2], h4.z, l4.z); split2(o[3], h4.w, l4.w);
        *(ushort4*)&xhi[node*HD + tj*4] = h4;
        *(ushort4*)&xlo[node*HD + tj*4] = l4;
    }
}

// ---------------- pq GEMM (MFMA, split-bf16 3-pass) ----------------
__global__ __launch_bounds__(256) void pq_gemm(
    const unsigned short* __restrict__ xhi, const unsigned short* __restrict__ xlo,
    const unsigned short* __restrict__ w1th, const unsigned short* __restrict__ w1tl,
    unsigned short* __restrict__ Ph, unsigned short* __restrict__ Qh)
{
    const int tid = threadIdx.x;
    const int l = tid & 63, w = tid >> 6;
    const int mr = l & 15, qd = l >> 4;
    const int n0 = blockIdx.x * 64;
    const int c0 = w * 64;

    f32x4 acc[4][4];
    #pragma unroll
    for (int mt = 0; mt < 4; ++mt)
        #pragma unroll
        for (int nt = 0; nt < 4; ++nt) acc[mt][nt] = (f32x4){0.f,0.f,0.f,0.f};

    #pragma unroll
    for (int ks = 0; ks < 4; ++ks) {
        const int kof = ks*32 + qd*8;
        bf16x8 ah[4], al[4], bh[4], bl[4];
        #pragma unroll
        for (int mt = 0; mt < 4; ++mt) {
            const int node = n0 + mt*16 + mr;
            ah[mt] = *(const bf16x8*)&xhi[node*HD + kof];
            al[mt] = *(const bf16x8*)&xlo[node*HD + kof];
        }
        #pragma unroll
        for (int nt = 0; nt < 4; ++nt) {
            const int c = c0 + nt*16 + mr;
            bh[nt] = *(const bf16x8*)&w1th[c*HD + kof];
            bl[nt] = *(const bf16x8*)&w1tl[c*HD + kof];
        }
        #pragma unroll
        for (int mt = 0; mt < 4; ++mt)
            #pragma unroll
            for (int nt = 0; nt < 4; ++nt) {
                acc[mt][nt] = __builtin_amdgcn_mfma_f32_16x16x32_bf16(ah[mt], bh[nt], acc[mt][nt], 0,0,0);
                acc[mt][nt] = __builtin_amdgcn_mfma_f32_16x16x32_bf16(ah[mt], bl[nt], acc[mt][nt], 0,0,0);
                acc[mt][nt] = __builtin_amdgcn_mfma_f32_16x16x32_bf16(al[mt], bh[nt], acc[mt][nt], 0,0,0);
            }
    }

    unsigned short* __restrict__ dst = (w < 2) ? Ph : Qh;
    const int cbase = (w < 2) ? c0 : c0 - 128;
    #pragma unroll
    for (int mt = 0; mt < 4; ++mt)
        #pragma unroll
        for (int nt = 0; nt < 4; ++nt) {
            const int cc = cbase + nt*16 + mr;
            #pragma unroll
            for (int r = 0; r < 4; ++r) {
                const int node = n0 + mt*16 + qd*4 + r;
                dst[(long)node*HD + cc] = f2h(acc[mt][nt][r]);
            }
        }
}

// ---------------- update GEMM (MFMA, split-bf16 3-pass) ----------------
__global__ __launch_bounds__(256) void upd_gemm(
    unsigned short* __restrict__ xhi, unsigned short* __restrict__ xlo,
    const float* __restrict__ msum, const int* __restrict__ degi,
    const unsigned short* __restrict__ wuth, const unsigned short* __restrict__ wutl,
    const float* __restrict__ bias)
{
    const int tid = threadIdx.x;
    const int l = tid & 63, w = tid >> 6;
    const int mr = l & 15, qd = l >> 4;
    const int n0 = blockIdx.x * 64 + w*16;
    const int node = n0 + mr;
    const float inv = 1.f / fmaxf((float)degi[node], 1.f);

    f32x4 acc[8];
    #pragma unroll
    for (int nt = 0; nt < 8; ++nt) acc[nt] = (f32x4){0.f,0.f,0.f,0.f};

    #pragma unroll 1
    for (int ks = 0; ks < 8; ++ks) {
        const int kof = ks*32 + qd*8;
        bf16x8 ah, al;
        if (ks < 4) {
            ah = *(const bf16x8*)&xhi[node*HD + kof];
            al = *(const bf16x8*)&xlo[node*HD + kof];
        } else {
            const int mk = kof - 128;
            const float4 v0 = *(const float4*)&msum[(long)node*HD + mk];
            const float4 v1 = *(const float4*)&msum[(long)node*HD + mk + 4];
            union { bf16x8 v; unsigned short u[8]; } hh, ll;
            float vv[8] = { v0.x*inv, v0.y*inv, v0.z*inv, v0.w*inv,
                            v1.x*inv, v1.y*inv, v1.z*inv, v1.w*inv };
            #pragma unroll
            for (int i = 0; i < 8; ++i) split2(vv[i], hh.u[i], ll.u[i]);
            ah = hh.v; al = ll.v;
        }
        #pragma unroll
        for (int nt = 0; nt < 8; ++nt) {
            const int c = nt*16 + mr;
            const bf16x8 bh = *(const bf16x8*)&wuth[c*256 + kof];
            const bf16x8 bl = *(const bf16x8*)&wutl[c*256 + kof];
            acc[nt] = __builtin_amdgcn_mfma_f32_16x16x32_bf16(ah, bh, acc[nt], 0,0,0);
            acc[nt] = __builtin_amdgcn_mfma_f32_16x16x32_bf16(ah, bl, acc[nt], 0,0,0);
            acc[nt] = __builtin_amdgcn_mfma_f32_16x16x32_bf16(al, bh, acc[nt], 0,0,0);
        }
    }

    #pragma unroll
    for (int nt = 0; nt < 8; ++nt) {
        const int c = nt*16 + mr;
        const float bb = bias[c];
        #pragma unroll
        for (int r = 0; r < 4; ++r) {
            const int nd = n0 + qd*4 + r;
            const float o = fmaxf(acc[nt][r] + bb, 0.f);
            unsigned short h, lo; split2(o, h, lo);
            xhi[nd*HD + c] = h;
            xlo[nd*HD + c] = lo;
        }
    }
}

// ---------------- fused edge kernel: XCD-swizzled blocks, packed-fp16 H, f16 MFMA --------
__global__ __launch_bounds__(256) void edge_msg_kernel(
    const unsigned short* __restrict__ Ph, const unsigned short* __restrict__ Qh,
    const float* __restrict__ posrel,
    const unsigned int* __restrict__ rcS,
    const float* __restrict__ w1c, const float* __restrict__ b1,
    const unsigned short* __restrict__ w2t,   // fp16 [128 n][128 k]
    const float* __restrict__ b2,
    float* __restrict__ msum)
{
    const int tid = threadIdx.x;
    // XCD-aware swizzle: dispatcher round-robins consecutive blocks across 8 XCDs;
    // remap so each XCD works a CONTIGUOUS edge range -> Q/rcS working set (~2 MB) fits its L2.
    const int bid = (blockIdx.x & 7) * 512 + (blockIdx.x >> 3);
    const long e0 = (long)bid * 256;
    const int l  = tid & 63;
    const int w  = tid >> 6;
    const int mr = l & 15;
    const int qd = l >> 4;
    const long ebase = e0 + w*64;

    const int aoff = ((mr >> 2) << 4) + (mr & 3);
    int ecol[4], erow[4];
    float edist[4];
    #pragma unroll
    for (int m = 0; m < 4; ++m) {
        const unsigned rc = rcS[ebase + aoff + m*4];
        erow[m] = (int)(rc >> 16); ecol[m] = (int)(rc & 0xffffu);
    }
    #pragma unroll
    for (int m = 0; m < 4; ++m) {
        const int c = ecol[m], r = erow[m];
        const float dx = posrel[c*3+0] - posrel[r*3+0];
        const float dy = posrel[c*3+1] - posrel[r*3+1];
        const float dz = posrel[c*3+2] - posrel[r*3+2];
        edist[m] = sqrtf(dx*dx + dy*dy + dz*dz);
    }

    unsigned rcv[16];
    {
        const uint4* rc4 = (const uint4*)&rcS[ebase + qd*16];
        #pragma unroll
        for (int i = 0; i < 4; ++i) {
            const uint4 v = rc4[i];
            rcv[i*4+0] = v.x >> 16; rcv[i*4+1] = v.y >> 16;
            rcv[i*4+2] = v.z >> 16; rcv[i*4+3] = v.w >> 16;
        }
    }
    // run-boundary bitmask (identical for all 8 col-tiles -> hoisted out of the t-loop)
    unsigned bmask = 0;
    #pragma unroll
    for (int j = 1; j < 16; ++j)
        if (rcv[j] != rcv[j-1]) bmask |= (1u << j);

    // ---- phase 1: H fragments in packed fp16 (_Float16 ext-vector math) ----
    f16x8 afr[4][4];
    const float4* __restrict__ c1f4 = (const float4*)w1c;
    const float4* __restrict__ b1f4 = (const float4*)b1;
    const f16x8 z8 = {};
    #pragma unroll
    for (int kk = 0; kk < 4; ++kk) {
        const int kof = kk*32 + qd*8;
        const int kb4 = kof >> 2;
        const float4 c0  = c1f4[kb4],   c1v = c1f4[kb4+1];
        const float4 b0  = b1f4[kb4],   b1v = b1f4[kb4+1];
        f16x8 c8, b8;
        c8[0] = (_Float16)c0.x;  c8[1] = (_Float16)c0.y;
        c8[2] = (_Float16)c0.z;  c8[3] = (_Float16)c0.w;
        c8[4] = (_Float16)c1v.x; c8[5] = (_Float16)c1v.y;
        c8[6] = (_Float16)c1v.z; c8[7] = (_Float16)c1v.w;
        b8[0] = (_Float16)b0.x;  b8[1] = (_Float16)b0.y;
        b8[2] = (_Float16)b0.z;  b8[3] = (_Float16)b0.w;
        b8[4] = (_Float16)b1v.x; b8[5] = (_Float16)b1v.y;
        b8[6] = (_Float16)b1v.z; b8[7] = (_Float16)b1v.w;
        #pragma unroll
        for (int m = 0; m < 4; ++m) {
            union { u16x8 raw; f16x8 v; } pu, qu;
            pu.raw = *(const u16x8*)&Ph[(long)ecol[m]*HD + kof];
            qu.raw = *(const u16x8*)&Qh[(long)erow[m]*HD + kof];
            const _Float16 d16 = (_Float16)edist[m];
            f16x8 s = pu.v + qu.v + b8 + d16 * c8;
            afr[m][kk] = __builtin_elementwise_max(s, z8);
        }
    }

    const f16x8* __restrict__ w2tv = (const f16x8*)w2t;
    f16x8 bfr[4];
    #pragma unroll
    for (int kk = 0; kk < 4; ++kk)
        bfr[kk] = w2tv[(0*16 + mr)*16 + kk*4 + qd];

    #pragma unroll 1
    for (int t = 0; t < 8; ++t) {
        f16x8 bnext[4];
        if (t < 7) {
            #pragma unroll
            for (int kk = 0; kk < 4; ++kk)
                bnext[kk] = w2tv[((t+1)*16 + mr)*16 + kk*4 + qd];
        }
        const int colg = t*16 + mr;
        const float bb = b2[colg];

        f32x4 acc[4];
        #pragma unroll
        for (int m = 0; m < 4; ++m) acc[m] = (f32x4){0.f, 0.f, 0.f, 0.f};
        #pragma unroll
        for (int kk = 0; kk < 4; ++kk)
            #pragma unroll
            for (int m = 0; m < 4; ++m)
                acc[m] = __builtin_amdgcn_mfma_f32_16x16x32_f16(afr[m][kk], bfr[kk], acc[m], 0, 0, 0);

        // scatter with precomputed run boundaries
        float run = fmaxf(acc[0][0] + bb, 0.f);
        #pragma unroll
        for (int j = 1; j < 16; ++j) {
            const float v = fmaxf(acc[j>>2][j&3] + bb, 0.f);
            if (bmask & (1u << j)) {
                atomAdd(&msum[(long)rcv[j-1]*HD + colg], run);
                run = v;
            } else {
                run += v;
            }
        }
        atomAdd(&msum[(long)rcv[15]*HD + colg], run);

        #pragma unroll
        for (int kk = 0; kk < 4; ++kk) bfr[kk] = bnext[kk];
    }
}

// ---------------- ligand-masked per-graph sum: batch-sorted run aggregation --------------
__global__ __launch_bounds__(256) void gsum_kernel(
    const unsigned short* __restrict__ xhi, const unsigned short* __restrict__ xlo,
    const int* __restrict__ batch,
    const int* __restrict__ ntype, float* __restrict__ gsum)
{
    const int tid = threadIdx.x;
    const int cg = tid & 31;          // float4 col group
    const int ns = tid >> 5;          // node strip 0..7
    const int n0 = blockIdx.x * 512 + ns * 64;

    int bprev = -1;
    float4 run = make_float4(0.f, 0.f, 0.f, 0.f);
    for (int i = 0; i < 64; ++i) {
        const int n = n0 + i;
        if (ntype[n] != 1) continue;
        const int b = batch[n];
        const ushort4 h  = *(const ushort4*)&xhi[(long)n*HD + cg*4];
        const ushort4 lo = *(const ushort4*)&xlo[(long)n*HD + cg*4];
        float4 v;
        v.x = bf2f(h.x) + bf2f(lo.x);
        v.y = bf2f(h.y) + bf2f(lo.y);
        v.z = bf2f(h.z) + bf2f(lo.z);
        v.w = bf2f(h.w) + bf2f(lo.w);
        if (b != bprev) {
            if (bprev >= 0) {
                float* dst = &gsum[bprev*HD + cg*4];
                atomAdd(dst+0, run.x); atomAdd(dst+1, run.y);
                atomAdd(dst+2, run.z); atomAdd(dst+3, run.w);
            }
            bprev = b; run = v;
        } else {
            run.x += v.x; run.y += v.y; run.z += v.z; run.w += v.w;
        }
    }
    if (bprev >= 0) {
        float* dst = &gsum[bprev*HD + cg*4];
        atomAdd(dst+0, run.x); atomAdd(dst+1, run.y);
        atomAdd(dst+2, run.z); atomAdd(dst+3, run.w);
    }
}

// ---------------- readout ----------------
__global__ __launch_bounds__(128) void readout_kernel(
    const float* __restrict__ gsum, const float* __restrict__ lcnt,
    const float* __restrict__ w1, const float* __restrict__ b1,
    const float* __restrict__ w2, const float* __restrict__ b2,
    float* __restrict__ out)
{
    __shared__ float gs[HD];
    __shared__ float red[2];
    const int b = blockIdx.x, j = threadIdx.x;
    gs[j] = gsum[b*HD + j] / fmaxf(lcnt[b], 1.f);
    __syncthreads();
    float acc = b1[j];
    for (int k = 0; k < HD; ++k) acc += gs[k]*w1[k*HD + j];
    float hg = fmaxf(acc, 0.f) * w2[j];
    #pragma unroll
    for (int off = 32; off > 0; off >>= 1) hg += __shfl_down(hg, off, 64);
    if ((j & 63) == 0) red[j >> 6] = hg;
    __syncthreads();
    if (j == 0) out[b] = red[0] + red[1] + b2[0];
}

extern "C" void kernel_launch(void* const* d_in, const int* in_sizes, int n_in,
                              void* d_out, int out_size, void* d_ws, size_t ws_size,
                              hipStream_t stream)
{
    const float* pos   = (const float*)d_in[0];
    const int*   z     = (const int*)d_in[1];
    const int*   batch = (const int*)d_in[2];
    const int*   eidx  = (const int*)d_in[3];
    const int*   ntype = (const int*)d_in[4];
    const float* emb   = (const float*)d_in[5];
    const float* lin_w = (const float*)d_in[6];
    const float* lin_b = (const float*)d_in[7];
    const float* mw1   = (const float*)d_in[8];
    const float* mb1   = (const float*)d_in[9];
    const float* mw2   = (const float*)d_in[10];
    const float* mb2   = (const float*)d_in[11];
    const float* uw    = (const float*)d_in[12];
    const float* ub    = (const float*)d_in[13];
    const float* rw1   = (const float*)d_in[14];
    const float* rb1   = (const float*)d_in[15];
    const float* rw2   = (const float*)d_in[16];
    const float* rb2   = (const float*)d_in[17];

    const int* row = eidx;
    const int* col = eidx + NE;

    float* ws     = (float*)d_ws;
    float* csum   = ws + O_CSUM;
    float* ccnt   = ws + O_CCNT;
    float* lcnt   = ws + O_LCNT;
    float* gsum   = ws + O_GSUM;
    int*   degi   = (int*)(ws + O_DEGI);
    float* posrel = ws + O_POSREL;
    unsigned int* rcS = (unsigned int*)(ws + O_RC);
    unsigned short* xhi = (unsigned short*)(ws + O_XHI);
    unsigned short* xlo = (unsigned short*)(ws + O_XLO);
    unsigned short* Ph  = (unsigned short*)(ws + O_P);
    unsigned short* Qh  = (unsigned short*)(ws + O_Q);
    float* msum   = ws + O_MSUM;
    unsigned short* w2t  = (unsigned short*)(ws + O_W2T);
    unsigned short* w1th = (unsigned short*)(ws + O_W1TH);
    unsigned short* w1tl = (unsigned short*)(ws + O_W1TL);
    unsigned short* wuth = (unsigned short*)(ws + O_WUTH);
    unsigned short* wutl = (unsigned short*)(ws + O_WUTL);
    int* chunkSum = (int*)(ws + O_CHK);
    int* rowStart = (int*)xhi;           // alias xhi head pre-lin_in
    int* cnt      = (int*)xhi + NN;

    (void)hipMemsetAsync(ws, 0, (size_t)(O_DEGI + NN) * sizeof(float), stream);
    (void)hipMemsetAsync(cnt, 0, (size_t)NN * sizeof(int), stream);

    stats_kernel  <<<NN/256, 256, 0, stream>>>(pos, batch, ntype, csum, ccnt, lcnt);
    deg_kernel    <<<NE/256, 256, 0, stream>>>(row, degi);
    posrel_kernel <<<NN/256, 256, 0, stream>>>(pos, batch, csum, ccnt, posrel);
    scanA_kernel  <<<256, 256, 0, stream>>>(degi, chunkSum);
    scanB_kernel  <<<1, 256, 0, stream>>>(chunkSum);
    scanC_kernel  <<<256, 256, 0, stream>>>(degi, chunkSum, rowStart);
    scatter_kernel<<<NE/256, 256, 0, stream>>>(row, col, rowStart, cnt, rcS);
    wprep_kernel  <<<384, 256, 0, stream>>>(mw1, uw, mw2, w1th, w1tl, wuth, wutl, w2t);

    lin_in_gemm<<<NN/32, 256, 0, stream>>>(emb, posrel, z, lin_w, lin_b, xhi, xlo);

    for (int l = 0; l < NL; ++l) {
        const float* W1 = mw1 + (size_t)l*257*HD;
        pq_gemm<<<NN/64, 256, 0, stream>>>(xhi, xlo, w1th + (size_t)l*32768, w1tl + (size_t)l*32768, Ph, Qh);
        (void)hipMemsetAsync(msum, 0, (size_t)NN*HD*sizeof(float), stream);
        edge_msg_kernel<<<NE/256, 256, 0, stream>>>(Ph, Qh, posrel, rcS,
                                                    W1 + 256*HD, mb1 + l*HD,
                                                    w2t + (size_t)l*16384, mb2 + l*HD, msum);
        upd_gemm<<<NN/64, 256, 0, stream>>>(xhi, xlo, msum, degi,
                                            wuth + (size_t)l*32768, wutl + (size_t)l*32768,
                                            ub + l*HD);
    }

    gsum_kernel   <<<NN/512, 256, 0, stream>>>(xhi, xlo, batch, ntype, gsum);
    readout_kernel<<<NB, 128, 0, stream>>>(gsum, lcnt, rw1, rb1, rw2, rb2, (float*)d_out);
}

// Round 16
// 993.393 us; speedup vs baseline: 1.0387x; 1.0387x over previous
//
#include <hip/hip_runtime.h>
#include <hip/hip_bf16.h>
#include <hip/hip_fp16.h>
#include <math.h>

#define NN 65536
#define NE 1048576
#define NB 64
#define HD 128
#define NL 3

// ---- workspace layout (float offsets) ----
#define O_CSUM   0
#define O_CCNT   192
#define O_LCNT   256
#define O_GSUM   320         // -> 8512
#define O_DEGI   8512        // -> 74048
#define O_POSREL 74048       // -> 270656
#define O_RC     270656      // -> 1319232
#define O_XHI    1319232     // NN*128 ushort -> 5513536
#define O_XLO    5513536     // -> 9707840
#define O_P      9707840     // NN*128 fp16 -> 18096448
#define O_Q      18096448    // -> 26485056
#define O_MSUM   26485056    // -> 34873664
#define O_W2T    34873664    // 3*128*128 fp16 -> 34898240
#define O_W1TH   34898240    // -> 34947392
#define O_W1TL   34947392    // -> 34996544
#define O_WUTH   34996544    // -> 35045696
#define O_WUTL   35045696    // -> 35094848
#define O_CHK    35094848    // 256 ints -> 35095104 (~140.4 MB)

typedef __attribute__((ext_vector_type(8))) short bf16x8;
typedef __attribute__((ext_vector_type(8))) _Float16 f16x8;
typedef __attribute__((ext_vector_type(8))) unsigned short u16x8;
typedef __attribute__((ext_vector_type(4))) float f32x4;

__device__ __forceinline__ void atomAdd(float* p, float v) { unsafeAtomicAdd(p, v); }

__device__ __forceinline__ unsigned short f2bf(float f) {
    union { __hip_bfloat16 h; unsigned short u; } cv;
    cv.h = __float2bfloat16(f);
    return cv.u;
}
__device__ __forceinline__ float bf2f(unsigned short u) {
    union { float f; unsigned v; } c; c.v = ((unsigned)u) << 16; return c.f;
}
__device__ __forceinline__ void split2(float v, unsigned short& h, unsigned short& l) {
    h = f2bf(v); l = f2bf(v - bf2f(h));
}
__device__ __forceinline__ unsigned short f2h(float f) {
    union { __half h; unsigned short u; } c; c.h = __float2half(f); return c.u;
}

// ---------------- stats ----------------
__global__ __launch_bounds__(256) void stats_kernel(
    const float* __restrict__ pos, const int* __restrict__ batch,
    const int* __restrict__ ntype,
    float* __restrict__ csum, float* __restrict__ ccnt, float* __restrict__ lcnt)
{
    __shared__ float s[NB * 5];
    const int tid = threadIdx.x;
    for (int i = tid; i < NB * 5; i += 256) s[i] = 0.f;
    __syncthreads();
    const int n = blockIdx.x * 256 + tid;
    const int b = batch[n];
    atomicAdd(&s[b*5+0], pos[n*3+0]);
    atomicAdd(&s[b*5+1], pos[n*3+1]);
    atomicAdd(&s[b*5+2], pos[n*3+2]);
    atomicAdd(&s[b*5+3], 1.f);
    if (ntype[n] == 1) atomicAdd(&s[b*5+4], 1.f);
    __syncthreads();
    for (int i = tid; i < NB * 5; i += 256) {
        float v = s[i];
        if (v != 0.f) {
            int b2 = i / 5, f = i - b2*5;
            if (f < 3)       atomAdd(&csum[b2*3+f], v);
            else if (f == 3) atomAdd(&ccnt[b2], v);
            else             atomAdd(&lcnt[b2], v);
        }
    }
}

// ---------------- degree histogram ----------------
__global__ __launch_bounds__(256) void deg_kernel(const int* __restrict__ row, int* __restrict__ degi)
{
    const int e = blockIdx.x * 256 + threadIdx.x;
    atomicAdd(&degi[row[e]], 1);
}

// ---------------- two-level scan ----------------
__global__ __launch_bounds__(256) void scanA_kernel(const int* __restrict__ degi, int* __restrict__ chunkSum)
{
    __shared__ int red[4];
    const int t = threadIdx.x, b = blockIdx.x;
    int v = degi[b*256 + t];
    #pragma unroll
    for (int off = 32; off > 0; off >>= 1) v += __shfl_down(v, off, 64);
    if ((t & 63) == 0) red[t >> 6] = v;
    __syncthreads();
    if (t == 0) chunkSum[b] = red[0] + red[1] + red[2] + red[3];
}

__global__ __launch_bounds__(256) void scanB_kernel(int* __restrict__ chunkSum)
{
    __shared__ int s[256];
    const int t = threadIdx.x;
    const int v = chunkSum[t];
    s[t] = v;
    __syncthreads();
    #pragma unroll
    for (int off = 1; off < 256; off <<= 1) {
        int u = (t >= off) ? s[t - off] : 0;
        __syncthreads();
        s[t] += u;
        __syncthreads();
    }
    chunkSum[t] = s[t] - v;   // exclusive
}

__global__ __launch_bounds__(256) void scanC_kernel(const int* __restrict__ degi,
                                                    const int* __restrict__ chunkOff,
                                                    int* __restrict__ rowStart)
{
    __shared__ int s[256];
    const int t = threadIdx.x, b = blockIdx.x;
    const int v = degi[b*256 + t];
    s[t] = v;
    __syncthreads();
    #pragma unroll
    for (int off = 1; off < 256; off <<= 1) {
        int u = (t >= off) ? s[t - off] : 0;
        __syncthreads();
        s[t] += u;
        __syncthreads();
    }
    rowStart[b*256 + t] = chunkOff[b] + s[t] - v;
}

// ---------------- counting-sort scatter ----------------
__global__ __launch_bounds__(256) void scatter_kernel(
    const int* __restrict__ row, const int* __restrict__ col,
    const int* __restrict__ rowStart, int* __restrict__ cnt,
    unsigned int* __restrict__ rcS)
{
    const int e = blockIdx.x * 256 + threadIdx.x;
    const int r = row[e], c = col[e];
    const int p = rowStart[r] + atomicAdd(&cnt[r], 1);
    rcS[p] = ((unsigned)r << 16) | (unsigned)c;
}

// ---------------- pos_rel ----------------
__global__ __launch_bounds__(256) void posrel_kernel(
    const float* __restrict__ pos, const int* __restrict__ batch,
    const float* __restrict__ csum, const float* __restrict__ ccnt,
    float* __restrict__ posrel)
{
    const int n = blockIdx.x * 256 + threadIdx.x;
    const int b = batch[n];
    const float inv = 1.f / fmaxf(ccnt[b], 1.f);
    posrel[n*3+0] = pos[n*3+0] - csum[b*3+0]*inv;
    posrel[n*3+1] = pos[n*3+1] - csum[b*3+1]*inv;
    posrel[n*3+2] = pos[n*3+2] - csum[b*3+2]*inv;
}

// ---------------- weight prep (W2T fp16) ----------------
__global__ __launch_bounds__(256) void wprep_kernel(
    const float* __restrict__ mw1, const float* __restrict__ uw,
    const float* __restrict__ mw2,
    unsigned short* __restrict__ w1th, unsigned short* __restrict__ w1tl,
    unsigned short* __restrict__ wuth, unsigned short* __restrict__ wutl,
    unsigned short* __restrict__ w2t)
{
    const int idx = blockIdx.x * 256 + threadIdx.x;   // 98304
    {   // W1T: [l][c<256][k<128]
        const int l = idx >> 15, rem = idx & 32767, c = rem >> 7, k = rem & 127;
        const int kk = (c < 128) ? k : (128 + k);
        const int cc = c & 127;
        const float v = mw1[l*257*128 + kk*128 + cc];
        unsigned short h, lo; split2(v, h, lo);
        w1th[idx] = h; w1tl[idx] = lo;
    }
    {   // WuT: [l][c<128][k<256] = uw[l][k][c]
        const int l = idx >> 15, rem = idx & 32767, c = rem >> 8, k = rem & 255;
        const float v = uw[l*256*128 + k*128 + c];
        unsigned short h, lo; split2(v, h, lo);
        wuth[idx] = h; wutl[idx] = lo;
    }
    if (idx < 49152) {   // W2T fp16: [l][n][k] = mw2[l][k][n]
        const int l = idx >> 14, rem = idx & 16383, n = rem >> 7, k = rem & 127;
        w2t[idx] = f2h(mw2[(l << 14) + k*128 + n]);
    }
}

// ---------------- lin_in ----------------
__global__ __launch_bounds__(256) void lin_in_gemm(
    const float* __restrict__ emb, const float* __restrict__ posrel,
    const int* __restrict__ zidx,
    const float* __restrict__ W, const float* __restrict__ bias,
    unsigned short* __restrict__ xhi, unsigned short* __restrict__ xlo)
{
    __shared__ __align__(16) float Asm[32][132];
    __shared__ __align__(16) float Wsm[32][128];
    const int tid = threadIdx.x;
    const int n0  = blockIdx.x * 32;
    const float4* __restrict__ A0f4 = (const float4*)emb;

    for (int idx4 = tid; idx4 < 1024; idx4 += 256) {
        int i = idx4 >> 5, k4 = idx4 & 31;
        int zz = zidx[n0 + i];
        *(float4*)&Asm[i][k4*4] = A0f4[zz*32 + k4];
    }
    if (tid < 96) { int i = tid / 3, d = tid - i*3; Asm[i][128+d] = posrel[(n0+i)*3 + d]; }
    else if (tid < 128) { Asm[tid-96][131] = 0.f; }

    const int tj = tid & 31;
    const int tn = tid >> 5;
    float acc[4][4];
    #pragma unroll
    for (int r = 0; r < 4; ++r)
        #pragma unroll
        for (int c = 0; c < 4; ++c) acc[r][c] = 0.f;

    const float4* __restrict__ Wf4 = (const float4*)W;
    #pragma unroll 1
    for (int kc = 0; kc < 131; kc += 32) {
        const int kend = (131 - kc < 32) ? (131 - kc) : 32;
        __syncthreads();
        for (int idx4 = tid; idx4 < kend*32; idx4 += 256) {
            int kk = idx4 >> 5, j4 = idx4 & 31;
            *(float4*)&Wsm[kk][j4*4] = Wf4[(kc+kk)*32 + j4];
        }
        __syncthreads();
        for (int kk = 0; kk < kend; ++kk) {
            const float4 w = *(const float4*)&Wsm[kk][tj*4];
            #pragma unroll
            for (int r = 0; r < 4; ++r) {
                const float a = Asm[tn*4+r][kc+kk];
                acc[r][0] += a*w.x; acc[r][1] += a*w.y; acc[r][2] += a*w.z; acc[r][3] += a*w.w;
            }
        }
    }

    const float4 bias4 = ((const float4*)bias)[tj];
    #pragma unroll
    for (int r = 0; r < 4; ++r) {
        const int node = n0 + tn*4 + r;
        const float o[4] = { acc[r][0] + bias4.x, acc[r][1] + bias4.y,
                             acc[r][2] + bias4.z, acc[r][3] + bias4.w };
        ushort4 h4, l4;
        split2(o[0], h4.x, l4.x); split2(o[1], h4.y, l4.y);
        split2(o[2], h4.z, l4.z); split2(o[3], h4.w, l4.w);
        *(ushort4*)&xhi[node*HD + tj*4] = h4;
        *(ushort4*)&xlo[node*HD + tj*4] = l4;
    }
}

// ---------------- pq GEMM (MFMA, split-bf16 3-pass) ----------------
__global__ __launch_bounds__(256) void pq_gemm(
    const unsigned short* __restrict__ xhi, const unsigned short* __restrict__ xlo,
    const unsigned short* __restrict__ w1th, const unsigned short* __restrict__ w1tl,
    unsigned short* __restrict__ Ph, unsigned short* __restrict__ Qh)
{
    const int tid = threadIdx.x;
    const int l = tid & 63, w = tid >> 6;
    const int mr = l & 15, qd = l >> 4;
    const int n0 = blockIdx.x * 64;
    const int c0 = w * 64;

    f32x4 acc[4][4];
    #pragma unroll
    for (int mt = 0; mt < 4; ++mt)
        #pragma unroll
        for (int nt = 0; nt < 4; ++nt) acc[mt][nt] = (f32x4){0.f,0.f,0.f,0.f};

    #pragma unroll
    for (int ks = 0; ks < 4; ++ks) {
        const int kof = ks*32 + qd*8;
        bf16x8 ah[4], al[4], bh[4], bl[4];
        #pragma unroll
        for (int mt = 0; mt < 4; ++mt) {
            const int node = n0 + mt*16 + mr;
            ah[mt] = *(const bf16x8*)&xhi[node*HD + kof];
            al[mt] = *(const bf16x8*)&xlo[node*HD + kof];
        }
        #pragma unroll
        for (int nt = 0; nt < 4; ++nt) {
            const int c = c0 + nt*16 + mr;
            bh[nt] = *(const bf16x8*)&w1th[c*HD + kof];
            bl[nt] = *(const bf16x8*)&w1tl[c*HD + kof];
        }
        #pragma unroll
        for (int mt = 0; mt < 4; ++mt)
            #pragma unroll
            for (int nt = 0; nt < 4; ++nt) {
                acc[mt][nt] = __builtin_amdgcn_mfma_f32_16x16x32_bf16(ah[mt], bh[nt], acc[mt][nt], 0,0,0);
                acc[mt][nt] = __builtin_amdgcn_mfma_f32_16x16x32_bf16(ah[mt], bl[nt], acc[mt][nt], 0,0,0);
                acc[mt][nt] = __builtin_amdgcn_mfma_f32_16x16x32_bf16(al[mt], bh[nt], acc[mt][nt], 0,0,0);
            }
    }

    unsigned short* __restrict__ dst = (w < 2) ? Ph : Qh;
    const int cbase = (w < 2) ? c0 : c0 - 128;
    #pragma unroll
    for (int mt = 0; mt < 4; ++mt)
        #pragma unroll
        for (int nt = 0; nt < 4; ++nt) {
            const int cc = cbase + nt*16 + mr;
            #pragma unroll
            for (int r = 0; r < 4; ++r) {
                const int node = n0 + mt*16 + qd*4 + r;
                dst[(long)node*HD + cc] = f2h(acc[mt][nt][r]);
            }
        }
}

// ---------------- update GEMM (MFMA, split-bf16 3-pass) ----------------
__global__ __launch_bounds__(256) void upd_gemm(
    unsigned short* __restrict__ xhi, unsigned short* __restrict__ xlo,
    const float* __restrict__ msum, const int* __restrict__ degi,
    const unsigned short* __restrict__ wuth, const unsigned short* __restrict__ wutl,
    const float* __restrict__ bias)
{
    const int tid = threadIdx.x;
    const int l = tid & 63, w = tid >> 6;
    const int mr = l & 15, qd = l >> 4;
    const int n0 = blockIdx.x * 64 + w*16;
    const int node = n0 + mr;
    const float inv = 1.f / fmaxf((float)degi[node], 1.f);

    f32x4 acc[8];
    #pragma unroll
    for (int nt = 0; nt < 8; ++nt) acc[nt] = (f32x4){0.f,0.f,0.f,0.f};

    #pragma unroll 1
    for (int ks = 0; ks < 8; ++ks) {
        const int kof = ks*32 + qd*8;
        bf16x8 ah, al;
        if (ks < 4) {
            ah = *(const bf16x8*)&xhi[node*HD + kof];
            al = *(const bf16x8*)&xlo[node*HD + kof];
        } else {
            const int mk = kof - 128;
            const float4 v0 = *(const float4*)&msum[(long)node*HD + mk];
            const float4 v1 = *(const float4*)&msum[(long)node*HD + mk + 4];
            union { bf16x8 v; unsigned short u[8]; } hh, ll;
            float vv[8] = { v0.x*inv, v0.y*inv, v0.z*inv, v0.w*inv,
                            v1.x*inv, v1.y*inv, v1.z*inv, v1.w*inv };
            #pragma unroll
            for (int i = 0; i < 8; ++i) split2(vv[i], hh.u[i], ll.u[i]);
            ah = hh.v; al = ll.v;
        }
        #pragma unroll
        for (int nt = 0; nt < 8; ++nt) {
            const int c = nt*16 + mr;
            const bf16x8 bh = *(const bf16x8*)&wuth[c*256 + kof];
            const bf16x8 bl = *(const bf16x8*)&wutl[c*256 + kof];
            acc[nt] = __builtin_amdgcn_mfma_f32_16x16x32_bf16(ah, bh, acc[nt], 0,0,0);
            acc[nt] = __builtin_amdgcn_mfma_f32_16x16x32_bf16(ah, bl, acc[nt], 0,0,0);
            acc[nt] = __builtin_amdgcn_mfma_f32_16x16x32_bf16(al, bh, acc[nt], 0,0,0);
        }
    }

    #pragma unroll
    for (int nt = 0; nt < 8; ++nt) {
        const int c = nt*16 + mr;
        const float bb = bias[c];
        #pragma unroll
        for (int r = 0; r < 4; ++r) {
            const int nd = n0 + qd*4 + r;
            const float o = fmaxf(acc[nt][r] + bb, 0.f);
            unsigned short h, lo; split2(o, h, lo);
            xhi[nd*HD + c] = h;
            xlo[nd*HD + c] = lo;
        }
    }
}

// ---------------- fused edge kernel: packed-fp16 H build (_Float16 vectors) + f16 MFMA ----
__global__ __launch_bounds__(256) void edge_msg_kernel(
    const unsigned short* __restrict__ Ph, const unsigned short* __restrict__ Qh,
    const float* __restrict__ posrel,
    const unsigned int* __restrict__ rcS,
    const float* __restrict__ w1c, const float* __restrict__ b1,
    const unsigned short* __restrict__ w2t,   // fp16 [128 n][128 k]
    const float* __restrict__ b2,
    float* __restrict__ msum)
{
    const int tid = threadIdx.x;
    const long e0 = (long)blockIdx.x * 256;
    const int l  = tid & 63;
    const int w  = tid >> 6;
    const int mr = l & 15;
    const int qd = l >> 4;
    const long ebase = e0 + w*64;

    const int aoff = ((mr >> 2) << 4) + (mr & 3);
    int ecol[4], erow[4];
    float edist[4];
    #pragma unroll
    for (int m = 0; m < 4; ++m) {
        const unsigned rc = rcS[ebase + aoff + m*4];
        erow[m] = (int)(rc >> 16); ecol[m] = (int)(rc & 0xffffu);
    }
    #pragma unroll
    for (int m = 0; m < 4; ++m) {
        const int c = ecol[m], r = erow[m];
        const float dx = posrel[c*3+0] - posrel[r*3+0];
        const float dy = posrel[c*3+1] - posrel[r*3+1];
        const float dz = posrel[c*3+2] - posrel[r*3+2];
        edist[m] = sqrtf(dx*dx + dy*dy + dz*dz);
    }

    unsigned rcv[16];
    {
        const uint4* rc4 = (const uint4*)&rcS[ebase + qd*16];
        #pragma unroll
        for (int i = 0; i < 4; ++i) {
            const uint4 v = rc4[i];
            rcv[i*4+0] = v.x >> 16; rcv[i*4+1] = v.y >> 16;
            rcv[i*4+2] = v.z >> 16; rcv[i*4+3] = v.w >> 16;
        }
    }

    // ---- phase 1: H fragments in packed fp16 (_Float16 ext-vector math) ----
    f16x8 afr[4][4];
    const float4* __restrict__ c1f4 = (const float4*)w1c;
    const float4* __restrict__ b1f4 = (const float4*)b1;
    const f16x8 z8 = {};
    #pragma unroll
    for (int kk = 0; kk < 4; ++kk) {
        const int kof = kk*32 + qd*8;
        const int kb4 = kof >> 2;
        const float4 c0  = c1f4[kb4],   c1v = c1f4[kb4+1];
        const float4 b0  = b1f4[kb4],   b1v = b1f4[kb4+1];
        f16x8 c8, b8;
        c8[0] = (_Float16)c0.x;  c8[1] = (_Float16)c0.y;
        c8[2] = (_Float16)c0.z;  c8[3] = (_Float16)c0.w;
        c8[4] = (_Float16)c1v.x; c8[5] = (_Float16)c1v.y;
        c8[6] = (_Float16)c1v.z; c8[7] = (_Float16)c1v.w;
        b8[0] = (_Float16)b0.x;  b8[1] = (_Float16)b0.y;
        b8[2] = (_Float16)b0.z;  b8[3] = (_Float16)b0.w;
        b8[4] = (_Float16)b1v.x; b8[5] = (_Float16)b1v.y;
        b8[6] = (_Float16)b1v.z; b8[7] = (_Float16)b1v.w;
        #pragma unroll
        for (int m = 0; m < 4; ++m) {
            union { u16x8 raw; f16x8 v; } pu, qu;
            pu.raw = *(const u16x8*)&Ph[(long)ecol[m]*HD + kof];
            qu.raw = *(const u16x8*)&Qh[(long)erow[m]*HD + kof];
            const _Float16 d16 = (_Float16)edist[m];
            f16x8 s = pu.v + qu.v + b8 + d16 * c8;
            afr[m][kk] = __builtin_elementwise_max(s, z8);
        }
    }

    const f16x8* __restrict__ w2tv = (const f16x8*)w2t;
    f16x8 bfr[4];
    #pragma unroll
    for (int kk = 0; kk < 4; ++kk)
        bfr[kk] = w2tv[(0*16 + mr)*16 + kk*4 + qd];

    #pragma unroll 1
    for (int t = 0; t < 8; ++t) {
        f16x8 bnext[4];
        if (t < 7) {
            #pragma unroll
            for (int kk = 0; kk < 4; ++kk)
                bnext[kk] = w2tv[((t+1)*16 + mr)*16 + kk*4 + qd];
        }
        const int colg = t*16 + mr;
        const float bb = b2[colg];

        f32x4 acc[4];
        #pragma unroll
        for (int m = 0; m < 4; ++m) acc[m] = (f32x4){0.f, 0.f, 0.f, 0.f};
        #pragma unroll
        for (int kk = 0; kk < 4; ++kk)
            #pragma unroll
            for (int m = 0; m < 4; ++m)
                acc[m] = __builtin_amdgcn_mfma_f32_16x16x32_f16(afr[m][kk], bfr[kk], acc[m], 0, 0, 0);

        int rprev = -1;
        float run = 0.f;
        #pragma unroll
        for (int m = 0; m < 4; ++m) {
            #pragma unroll
            for (int r4 = 0; r4 < 4; ++r4) {
                const int rw = (int)rcv[m*4 + r4];
                const float v = fmaxf(acc[m][r4] + bb, 0.f);
                if (rw != rprev) {
                    if (rprev >= 0) atomAdd(&msum[(long)rprev*HD + colg], run);
                    rprev = rw; run = v;
                } else {
                    run += v;
                }
            }
        }
        atomAdd(&msum[(long)rprev*HD + colg], run);

        #pragma unroll
        for (int kk = 0; kk < 4; ++kk) bfr[kk] = bnext[kk];
    }
}

// ---------------- ligand-masked per-graph sum: batch-sorted run aggregation --------------
__global__ __launch_bounds__(256) void gsum_kernel(
    const unsigned short* __restrict__ xhi, const unsigned short* __restrict__ xlo,
    const int* __restrict__ batch,
    const int* __restrict__ ntype, float* __restrict__ gsum)
{
    const int tid = threadIdx.x;
    const int cg = tid & 31;          // float4 col group
    const int ns = tid >> 5;          // node strip 0..7
    const int n0 = blockIdx.x * 512 + ns * 64;

    int bprev = -1;
    float4 run = make_float4(0.f, 0.f, 0.f, 0.f);
    for (int i = 0; i < 64; ++i) {
        const int n = n0 + i;
        if (ntype[n] != 1) continue;
        const int b = batch[n];
        const ushort4 h  = *(const ushort4*)&xhi[(long)n*HD + cg*4];
        const ushort4 lo = *(const ushort4*)&xlo[(long)n*HD + cg*4];
        float4 v;
        v.x = bf2f(h.x) + bf2f(lo.x);
        v.y = bf2f(h.y) + bf2f(lo.y);
        v.z = bf2f(h.z) + bf2f(lo.z);
        v.w = bf2f(h.w) + bf2f(lo.w);
        if (b != bprev) {
            if (bprev >= 0) {
                float* dst = &gsum[bprev*HD + cg*4];
                atomAdd(dst+0, run.x); atomAdd(dst+1, run.y);
                atomAdd(dst+2, run.z); atomAdd(dst+3, run.w);
            }
            bprev = b; run = v;
        } else {
            run.x += v.x; run.y += v.y; run.z += v.z; run.w += v.w;
        }
    }
    if (bprev >= 0) {
        float* dst = &gsum[bprev*HD + cg*4];
        atomAdd(dst+0, run.x); atomAdd(dst+1, run.y);
        atomAdd(dst+2, run.z); atomAdd(dst+3, run.w);
    }
}

// ---------------- readout ----------------
__global__ __launch_bounds__(128) void readout_kernel(
    const float* __restrict__ gsum, const float* __restrict__ lcnt,
    const float* __restrict__ w1, const float* __restrict__ b1,
    const float* __restrict__ w2, const float* __restrict__ b2,
    float* __restrict__ out)
{
    __shared__ float gs[HD];
    __shared__ float red[2];
    const int b = blockIdx.x, j = threadIdx.x;
    gs[j] = gsum[b*HD + j] / fmaxf(lcnt[b], 1.f);
    __syncthreads();
    float acc = b1[j];
    for (int k = 0; k < HD; ++k) acc += gs[k]*w1[k*HD + j];
    float hg = fmaxf(acc, 0.f) * w2[j];
    #pragma unroll
    for (int off = 32; off > 0; off >>= 1) hg += __shfl_down(hg, off, 64);
    if ((j & 63) == 0) red[j >> 6] = hg;
    __syncthreads();
    if (j == 0) out[b] = red[0] + red[1] + b2[0];
}

extern "C" void kernel_launch(void* const* d_in, const int* in_sizes, int n_in,
                              void* d_out, int out_size, void* d_ws, size_t ws_size,
                              hipStream_t stream)
{
    const float* pos   = (const float*)d_in[0];
    const int*   z     = (const int*)d_in[1];
    const int*   batch = (const int*)d_in[2];
    const int*   eidx  = (const int*)d_in[3];
    const int*   ntype = (const int*)d_in[4];
    const float* emb   = (const float*)d_in[5];
    const float* lin_w = (const float*)d_in[6];
    const float* lin_b = (const float*)d_in[7];
    const float* mw1   = (const float*)d_in[8];
    const float* mb1   = (const float*)d_in[9];
    const float* mw2   = (const float*)d_in[10];
    const float* mb2   = (const float*)d_in[11];
    const float* uw    = (const float*)d_in[12];
    const float* ub    = (const float*)d_in[13];
    const float* rw1   = (const float*)d_in[14];
    const float* rb1   = (const float*)d_in[15];
    const float* rw2   = (const float*)d_in[16];
    const float* rb2   = (const float*)d_in[17];

    const int* row = eidx;
    const int* col = eidx + NE;

    float* ws     = (float*)d_ws;
    float* csum   = ws + O_CSUM;
    float* ccnt   = ws + O_CCNT;
    float* lcnt   = ws + O_LCNT;
    float* gsum   = ws + O_GSUM;
    int*   degi   = (int*)(ws + O_DEGI);
    float* posrel = ws + O_POSREL;
    unsigned int* rcS = (unsigned int*)(ws + O_RC);
    unsigned short* xhi = (unsigned short*)(ws + O_XHI);
    unsigned short* xlo = (unsigned short*)(ws + O_XLO);
    unsigned short* Ph  = (unsigned short*)(ws + O_P);
    unsigned short* Qh  = (unsigned short*)(ws + O_Q);
    float* msum   = ws + O_MSUM;
    unsigned short* w2t  = (unsigned short*)(ws + O_W2T);
    unsigned short* w1th = (unsigned short*)(ws + O_W1TH);
    unsigned short* w1tl = (unsigned short*)(ws + O_W1TL);
    unsigned short* wuth = (unsigned short*)(ws + O_WUTH);
    unsigned short* wutl = (unsigned short*)(ws + O_WUTL);
    int* chunkSum = (int*)(ws + O_CHK);
    int* rowStart = (int*)xhi;           // alias xhi head pre-lin_in
    int* cnt      = (int*)xhi + NN;

    (void)hipMemsetAsync(ws, 0, (size_t)(O_DEGI + NN) * sizeof(float), stream);
    (void)hipMemsetAsync(cnt, 0, (size_t)NN * sizeof(int), stream);

    stats_kernel  <<<NN/256, 256, 0, stream>>>(pos, batch, ntype, csum, ccnt, lcnt);
    deg_kernel    <<<NE/256, 256, 0, stream>>>(row, degi);
    posrel_kernel <<<NN/256, 256, 0, stream>>>(pos, batch, csum, ccnt, posrel);
    scanA_kernel  <<<256, 256, 0, stream>>>(degi, chunkSum);
    scanB_kernel  <<<1, 256, 0, stream>>>(chunkSum);
    scanC_kernel  <<<256, 256, 0, stream>>>(degi, chunkSum, rowStart);
    scatter_kernel<<<NE/256, 256, 0, stream>>>(row, col, rowStart, cnt, rcS);
    wprep_kernel  <<<384, 256, 0, stream>>>(mw1, uw, mw2, w1th, w1tl, wuth, wutl, w2t);

    lin_in_gemm<<<NN/32, 256, 0, stream>>>(emb, posrel, z, lin_w, lin_b, xhi, xlo);

    for (int l = 0; l < NL; ++l) {
        const float* W1 = mw1 + (size_t)l*257*HD;
        pq_gemm<<<NN/64, 256, 0, stream>>>(xhi, xlo, w1th + (size_t)l*32768, w1tl + (size_t)l*32768, Ph, Qh);
        (void)hipMemsetAsync(msum, 0, (size_t)NN*HD*sizeof(float), stream);
        edge_msg_kernel<<<NE/256, 256, 0, stream>>>(Ph, Qh, posrel, rcS,
                                                    W1 + 256*HD, mb1 + l*HD,
                                                    w2t + (size_t)l*16384, mb2 + l*HD, msum);
        upd_gemm<<<NN/64, 256, 0, stream>>>(xhi, xlo, msum, degi,
                                            wuth + (size_t)l*32768, wutl + (size_t)l*32768,
                                            ub + l*HD);
    }

    gsum_kernel   <<<NN/512, 256, 0, stream>>>(xhi, xlo, batch, ntype, gsum);
    readout_kernel<<<NB, 128, 0, stream>>>(gsum, lcnt, rw1, rb1, rw2, rb2, (float*)d_out);
}

// Round 17
// 978.519 us; speedup vs baseline: 1.0545x; 1.0152x over previous
//
#include <hip/hip_runtime.h>
#include <hip/hip_bf16.h>
#include <hip/hip_fp16.h>
#include <math.h>

#define NN 65536
#define NE 1048576
#define NB 64
#define HD 128
#define NL 3

// ---- workspace layout (float offsets) ----
#define O_CSUM   0
#define O_CCNT   192
#define O_LCNT   256
#define O_GSUM   320         // -> 8512
#define O_DEGI   8512        // -> 74048
#define O_POSREL 74048       // -> 270656
#define O_RC     270656      // -> 1319232
#define O_XHI    1319232     // NN*128 ushort -> 5513536
#define O_XLO    5513536     // -> 9707840
#define O_P      9707840     // NN*128 fp16 -> 18096448
#define O_Q      18096448    // -> 26485056
#define O_MSUM   26485056    // -> 34873664
#define O_W2T    34873664    // 3*128*128 fp16 -> 34898240
#define O_W1TH   34898240    // -> 34947392
#define O_W1TL   34947392    // -> 34996544
#define O_WUTH   34996544    // -> 35045696
#define O_WUTL   35045696    // -> 35094848
#define O_CHK    35094848    // 256 ints -> 35095104 (~140.4 MB)

typedef __attribute__((ext_vector_type(8))) short bf16x8;
typedef __attribute__((ext_vector_type(8))) _Float16 f16x8;
typedef __attribute__((ext_vector_type(8))) unsigned short u16x8;
typedef __attribute__((ext_vector_type(4))) float f32x4;

__device__ __forceinline__ void atomAdd(float* p, float v) { unsafeAtomicAdd(p, v); }

__device__ __forceinline__ unsigned short f2bf(float f) {
    union { __hip_bfloat16 h; unsigned short u; } cv;
    cv.h = __float2bfloat16(f);
    return cv.u;
}
__device__ __forceinline__ float bf2f(unsigned short u) {
    union { float f; unsigned v; } c; c.v = ((unsigned)u) << 16; return c.f;
}
__device__ __forceinline__ void split2(float v, unsigned short& h, unsigned short& l) {
    h = f2bf(v); l = f2bf(v - bf2f(h));
}
__device__ __forceinline__ unsigned short f2h(float f) {
    union { __half h; unsigned short u; } c; c.h = __float2half(f); return c.u;
}

// ---------------- stats ----------------
__global__ __launch_bounds__(256) void stats_kernel(
    const float* __restrict__ pos, const int* __restrict__ batch,
    const int* __restrict__ ntype,
    float* __restrict__ csum, float* __restrict__ ccnt, float* __restrict__ lcnt)
{
    __shared__ float s[NB * 5];
    const int tid = threadIdx.x;
    for (int i = tid; i < NB * 5; i += 256) s[i] = 0.f;
    __syncthreads();
    const int n = blockIdx.x * 256 + tid;
    const int b = batch[n];
    atomicAdd(&s[b*5+0], pos[n*3+0]);
    atomicAdd(&s[b*5+1], pos[n*3+1]);
    atomicAdd(&s[b*5+2], pos[n*3+2]);
    atomicAdd(&s[b*5+3], 1.f);
    if (ntype[n] == 1) atomicAdd(&s[b*5+4], 1.f);
    __syncthreads();
    for (int i = tid; i < NB * 5; i += 256) {
        float v = s[i];
        if (v != 0.f) {
            int b2 = i / 5, f = i - b2*5;
            if (f < 3)       atomAdd(&csum[b2*3+f], v);
            else if (f == 3) atomAdd(&ccnt[b2], v);
            else             atomAdd(&lcnt[b2], v);
        }
    }
}

// ---------------- degree histogram ----------------
__global__ __launch_bounds__(256) void deg_kernel(const int* __restrict__ row, int* __restrict__ degi)
{
    const int e = blockIdx.x * 256 + threadIdx.x;
    atomicAdd(&degi[row[e]], 1);
}

// ---------------- two-level scan ----------------
__global__ __launch_bounds__(256) void scanA_kernel(const int* __restrict__ degi, int* __restrict__ chunkSum)
{
    __shared__ int red[4];
    const int t = threadIdx.x, b = blockIdx.x;
    int v = degi[b*256 + t];
    #pragma unroll
    for (int off = 32; off > 0; off >>= 1) v += __shfl_down(v, off, 64);
    if ((t & 63) == 0) red[t >> 6] = v;
    __syncthreads();
    if (t == 0) chunkSum[b] = red[0] + red[1] + red[2] + red[3];
}

__global__ __launch_bounds__(256) void scanB_kernel(int* __restrict__ chunkSum)
{
    __shared__ int s[256];
    const int t = threadIdx.x;
    const int v = chunkSum[t];
    s[t] = v;
    __syncthreads();
    #pragma unroll
    for (int off = 1; off < 256; off <<= 1) {
        int u = (t >= off) ? s[t - off] : 0;
        __syncthreads();
        s[t] += u;
        __syncthreads();
    }
    chunkSum[t] = s[t] - v;   // exclusive
}

__global__ __launch_bounds__(256) void scanC_kernel(const int* __restrict__ degi,
                                                    const int* __restrict__ chunkOff,
                                                    int* __restrict__ rowStart)
{
    __shared__ int s[256];
    const int t = threadIdx.x, b = blockIdx.x;
    const int v = degi[b*256 + t];
    s[t] = v;
    __syncthreads();
    #pragma unroll
    for (int off = 1; off < 256; off <<= 1) {
        int u = (t >= off) ? s[t - off] : 0;
        __syncthreads();
        s[t] += u;
        __syncthreads();
    }
    rowStart[b*256 + t] = chunkOff[b] + s[t] - v;
}

// ---------------- counting-sort scatter ----------------
__global__ __launch_bounds__(256) void scatter_kernel(
    const int* __restrict__ row, const int* __restrict__ col,
    const int* __restrict__ rowStart, int* __restrict__ cnt,
    unsigned int* __restrict__ rcS)
{
    const int e = blockIdx.x * 256 + threadIdx.x;
    const int r = row[e], c = col[e];
    const int p = rowStart[r] + atomicAdd(&cnt[r], 1);
    rcS[p] = ((unsigned)r << 16) | (unsigned)c;
}

// ---------------- pos_rel ----------------
__global__ __launch_bounds__(256) void posrel_kernel(
    const float* __restrict__ pos, const int* __restrict__ batch,
    const float* __restrict__ csum, const float* __restrict__ ccnt,
    float* __restrict__ posrel)
{
    const int n = blockIdx.x * 256 + threadIdx.x;
    const int b = batch[n];
    const float inv = 1.f / fmaxf(ccnt[b], 1.f);
    posrel[n*3+0] = pos[n*3+0] - csum[b*3+0]*inv;
    posrel[n*3+1] = pos[n*3+1] - csum[b*3+1]*inv;
    posrel[n*3+2] = pos[n*3+2] - csum[b*3+2]*inv;
}

// ---------------- weight prep (W2T fp16) ----------------
__global__ __launch_bounds__(256) void wprep_kernel(
    const float* __restrict__ mw1, const float* __restrict__ uw,
    const float* __restrict__ mw2,
    unsigned short* __restrict__ w1th, unsigned short* __restrict__ w1tl,
    unsigned short* __restrict__ wuth, unsigned short* __restrict__ wutl,
    unsigned short* __restrict__ w2t)
{
    const int idx = blockIdx.x * 256 + threadIdx.x;   // 98304
    {   // W1T: [l][c<256][k<128]
        const int l = idx >> 15, rem = idx & 32767, c = rem >> 7, k = rem & 127;
        const int kk = (c < 128) ? k : (128 + k);
        const int cc = c & 127;
        const float v = mw1[l*257*128 + kk*128 + cc];
        unsigned short h, lo; split2(v, h, lo);
        w1th[idx] = h; w1tl[idx] = lo;
    }
    {   // WuT: [l][c<128][k<256] = uw[l][k][c]
        const int l = idx >> 15, rem = idx & 32767, c = rem >> 8, k = rem & 255;
        const float v = uw[l*256*128 + k*128 + c];
        unsigned short h, lo; split2(v, h, lo);
        wuth[idx] = h; wutl[idx] = lo;
    }
    if (idx < 49152) {   // W2T fp16: [l][n][k] = mw2[l][k][n]
        const int l = idx >> 14, rem = idx & 16383, n = rem >> 7, k = rem & 127;
        w2t[idx] = f2h(mw2[(l << 14) + k*128 + n]);
    }
}

// ---------------- lin_in ----------------
__global__ __launch_bounds__(256) void lin_in_gemm(
    const float* __restrict__ emb, const float* __restrict__ posrel,
    const int* __restrict__ zidx,
    const float* __restrict__ W, const float* __restrict__ bias,
    unsigned short* __restrict__ xhi, unsigned short* __restrict__ xlo)
{
    __shared__ __align__(16) float Asm[32][132];
    __shared__ __align__(16) float Wsm[32][128];
    const int tid = threadIdx.x;
    const int n0  = blockIdx.x * 32;
    const float4* __restrict__ A0f4 = (const float4*)emb;

    for (int idx4 = tid; idx4 < 1024; idx4 += 256) {
        int i = idx4 >> 5, k4 = idx4 & 31;
        int zz = zidx[n0 + i];
        *(float4*)&Asm[i][k4*4] = A0f4[zz*32 + k4];
    }
    if (tid < 96) { int i = tid / 3, d = tid - i*3; Asm[i][128+d] = posrel[(n0+i)*3 + d]; }
    else if (tid < 128) { Asm[tid-96][131] = 0.f; }

    const int tj = tid & 31;
    const int tn = tid >> 5;
    float acc[4][4];
    #pragma unroll
    for (int r = 0; r < 4; ++r)
        #pragma unroll
        for (int c = 0; c < 4; ++c) acc[r][c] = 0.f;

    const float4* __restrict__ Wf4 = (const float4*)W;
    #pragma unroll 1
    for (int kc = 0; kc < 131; kc += 32) {
        const int kend = (131 - kc < 32) ? (131 - kc) : 32;
        __syncthreads();
        for (int idx4 = tid; idx4 < kend*32; idx4 += 256) {
            int kk = idx4 >> 5, j4 = idx4 & 31;
            *(float4*)&Wsm[kk][j4*4] = Wf4[(kc+kk)*32 + j4];
        }
        __syncthreads();
        for (int kk = 0; kk < kend; ++kk) {
            const float4 w = *(const float4*)&Wsm[kk][tj*4];
            #pragma unroll
            for (int r = 0; r < 4; ++r) {
                const float a = Asm[tn*4+r][kc+kk];
                acc[r][0] += a*w.x; acc[r][1] += a*w.y; acc[r][2] += a*w.z; acc[r][3] += a*w.w;
            }
        }
    }

    const float4 bias4 = ((const float4*)bias)[tj];
    #pragma unroll
    for (int r = 0; r < 4; ++r) {
        const int node = n0 + tn*4 + r;
        const float o[4] = { acc[r][0] + bias4.x, acc[r][1] + bias4.y,
                             acc[r][2] + bias4.z, acc[r][3] + bias4.w };
        ushort4 h4, l4;
        split2(o[0], h4.x, l4.x); split2(o[1], h4.y, l4.y);
        split2(o[2], h4.z, l4.z); split2(o[3], h4.w, l4.w);
        *(ushort4*)&xhi[node*HD + tj*4] = h4;
        *(ushort4*)&xlo[node*HD + tj*4] = l4;
    }
}

// ---------------- pq GEMM (MFMA, split-bf16 3-pass) + msum zeroing fused ----------------
__global__ __launch_bounds__(256) void pq_gemm(
    const unsigned short* __restrict__ xhi, const unsigned short* __restrict__ xlo,
    const unsigned short* __restrict__ w1th, const unsigned short* __restrict__ w1tl,
    unsigned short* __restrict__ Ph, unsigned short* __restrict__ Qh,
    float* __restrict__ msum)
{
    const int tid = threadIdx.x;
    const int l = tid & 63, w = tid >> 6;
    const int mr = l & 15, qd = l >> 4;
    const int n0 = blockIdx.x * 64;
    const int c0 = w * 64;

    // fused msum zeroing: this block owns a 32 KB slice (8192 floats = 2048 float4)
    {
        float4* mz = (float4*)&msum[(long)blockIdx.x * 8192];
        const float4 z4 = make_float4(0.f, 0.f, 0.f, 0.f);
        #pragma unroll
        for (int it = 0; it < 8; ++it) mz[tid + it*256] = z4;
    }

    f32x4 acc[4][4];
    #pragma unroll
    for (int mt = 0; mt < 4; ++mt)
        #pragma unroll
        for (int nt = 0; nt < 4; ++nt) acc[mt][nt] = (f32x4){0.f,0.f,0.f,0.f};

    #pragma unroll
    for (int ks = 0; ks < 4; ++ks) {
        const int kof = ks*32 + qd*8;
        bf16x8 ah[4], al[4], bh[4], bl[4];
        #pragma unroll
        for (int mt = 0; mt < 4; ++mt) {
            const int node = n0 + mt*16 + mr;
            ah[mt] = *(const bf16x8*)&xhi[node*HD + kof];
            al[mt] = *(const bf16x8*)&xlo[node*HD + kof];
        }
        #pragma unroll
        for (int nt = 0; nt < 4; ++nt) {
            const int c = c0 + nt*16 + mr;
            bh[nt] = *(const bf16x8*)&w1th[c*HD + kof];
            bl[nt] = *(const bf16x8*)&w1tl[c*HD + kof];
        }
        #pragma unroll
        for (int mt = 0; mt < 4; ++mt)
            #pragma unroll
            for (int nt = 0; nt < 4; ++nt) {
                acc[mt][nt] = __builtin_amdgcn_mfma_f32_16x16x32_bf16(ah[mt], bh[nt], acc[mt][nt], 0,0,0);
                acc[mt][nt] = __builtin_amdgcn_mfma_f32_16x16x32_bf16(ah[mt], bl[nt], acc[mt][nt], 0,0,0);
                acc[mt][nt] = __builtin_amdgcn_mfma_f32_16x16x32_bf16(al[mt], bh[nt], acc[mt][nt], 0,0,0);
            }
    }

    unsigned short* __restrict__ dst = (w < 2) ? Ph : Qh;
    const int cbase = (w < 2) ? c0 : c0 - 128;
    #pragma unroll
    for (int mt = 0; mt < 4; ++mt)
        #pragma unroll
        for (int nt = 0; nt < 4; ++nt) {
            const int cc = cbase + nt*16 + mr;
            #pragma unroll
            for (int r = 0; r < 4; ++r) {
                const int node = n0 + mt*16 + qd*4 + r;
                dst[(long)node*HD + cc] = f2h(acc[mt][nt][r]);
            }
        }
}

// ---------------- update GEMM (MFMA, split-bf16 3-pass) ----------------
__global__ __launch_bounds__(256) void upd_gemm(
    unsigned short* __restrict__ xhi, unsigned short* __restrict__ xlo,
    const float* __restrict__ msum, const int* __restrict__ degi,
    const unsigned short* __restrict__ wuth, const unsigned short* __restrict__ wutl,
    const float* __restrict__ bias)
{
    const int tid = threadIdx.x;
    const int l = tid & 63, w = tid >> 6;
    const int mr = l & 15, qd = l >> 4;
    const int n0 = blockIdx.x * 64 + w*16;
    const int node = n0 + mr;
    const float inv = 1.f / fmaxf((float)degi[node], 1.f);

    f32x4 acc[8];
    #pragma unroll
    for (int nt = 0; nt < 8; ++nt) acc[nt] = (f32x4){0.f,0.f,0.f,0.f};

    #pragma unroll 1
    for (int ks = 0; ks < 8; ++ks) {
        const int kof = ks*32 + qd*8;
        bf16x8 ah, al;
        if (ks < 4) {
            ah = *(const bf16x8*)&xhi[node*HD + kof];
            al = *(const bf16x8*)&xlo[node*HD + kof];
        } else {
            const int mk = kof - 128;
            const float4 v0 = *(const float4*)&msum[(long)node*HD + mk];
            const float4 v1 = *(const float4*)&msum[(long)node*HD + mk + 4];
            union { bf16x8 v; unsigned short u[8]; } hh, ll;
            float vv[8] = { v0.x*inv, v0.y*inv, v0.z*inv, v0.w*inv,
                            v1.x*inv, v1.y*inv, v1.z*inv, v1.w*inv };
            #pragma unroll
            for (int i = 0; i < 8; ++i) split2(vv[i], hh.u[i], ll.u[i]);
            ah = hh.v; al = ll.v;
        }
        #pragma unroll
        for (int nt = 0; nt < 8; ++nt) {
            const int c = nt*16 + mr;
            const bf16x8 bh = *(const bf16x8*)&wuth[c*256 + kof];
            const bf16x8 bl = *(const bf16x8*)&wutl[c*256 + kof];
            acc[nt] = __builtin_amdgcn_mfma_f32_16x16x32_bf16(ah, bh, acc[nt], 0,0,0);
            acc[nt] = __builtin_amdgcn_mfma_f32_16x16x32_bf16(ah, bl, acc[nt], 0,0,0);
            acc[nt] = __builtin_amdgcn_mfma_f32_16x16x32_bf16(al, bh, acc[nt], 0,0,0);
        }
    }

    #pragma unroll
    for (int nt = 0; nt < 8; ++nt) {
        const int c = nt*16 + mr;
        const float bb = bias[c];
        #pragma unroll
        for (int r = 0; r < 4; ++r) {
            const int nd = n0 + qd*4 + r;
            const float o = fmaxf(acc[nt][r] + bb, 0.f);
            unsigned short h, lo; split2(o, h, lo);
            xhi[nd*HD + c] = h;
            xlo[nd*HD + c] = lo;
        }
    }
}

// ---------------- fused edge kernel: packed-fp16 H build (_Float16 vectors) + f16 MFMA ----
__global__ __launch_bounds__(256) void edge_msg_kernel(
    const unsigned short* __restrict__ Ph, const unsigned short* __restrict__ Qh,
    const float* __restrict__ posrel,
    const unsigned int* __restrict__ rcS,
    const float* __restrict__ w1c, const float* __restrict__ b1,
    const unsigned short* __restrict__ w2t,   // fp16 [128 n][128 k]
    const float* __restrict__ b2,
    float* __restrict__ msum)
{
    const int tid = threadIdx.x;
    const long e0 = (long)blockIdx.x * 256;
    const int l  = tid & 63;
    const int w  = tid >> 6;
    const int mr = l & 15;
    const int qd = l >> 4;
    const long ebase = e0 + w*64;

    const int aoff = ((mr >> 2) << 4) + (mr & 3);
    int ecol[4], erow[4];
    float edist[4];
    #pragma unroll
    for (int m = 0; m < 4; ++m) {
        const unsigned rc = rcS[ebase + aoff + m*4];
        erow[m] = (int)(rc >> 16); ecol[m] = (int)(rc & 0xffffu);
    }
    #pragma unroll
    for (int m = 0; m < 4; ++m) {
        const int c = ecol[m], r = erow[m];
        const float dx = posrel[c*3+0] - posrel[r*3+0];
        const float dy = posrel[c*3+1] - posrel[r*3+1];
        const float dz = posrel[c*3+2] - posrel[r*3+2];
        edist[m] = sqrtf(dx*dx + dy*dy + dz*dz);
    }

    unsigned rcv[16];
    {
        const uint4* rc4 = (const uint4*)&rcS[ebase + qd*16];
        #pragma unroll
        for (int i = 0; i < 4; ++i) {
            const uint4 v = rc4[i];
            rcv[i*4+0] = v.x >> 16; rcv[i*4+1] = v.y >> 16;
            rcv[i*4+2] = v.z >> 16; rcv[i*4+3] = v.w >> 16;
        }
    }

    // ---- phase 1: H fragments in packed fp16 (_Float16 ext-vector math) ----
    f16x8 afr[4][4];
    const float4* __restrict__ c1f4 = (const float4*)w1c;
    const float4* __restrict__ b1f4 = (const float4*)b1;
    const f16x8 z8 = {};
    #pragma unroll
    for (int kk = 0; kk < 4; ++kk) {
        const int kof = kk*32 + qd*8;
        const int kb4 = kof >> 2;
        const float4 c0  = c1f4[kb4],   c1v = c1f4[kb4+1];
        const float4 b0  = b1f4[kb4],   b1v = b1f4[kb4+1];
        f16x8 c8, b8;
        c8[0] = (_Float16)c0.x;  c8[1] = (_Float16)c0.y;
        c8[2] = (_Float16)c0.z;  c8[3] = (_Float16)c0.w;
        c8[4] = (_Float16)c1v.x; c8[5] = (_Float16)c1v.y;
        c8[6] = (_Float16)c1v.z; c8[7] = (_Float16)c1v.w;
        b8[0] = (_Float16)b0.x;  b8[1] = (_Float16)b0.y;
        b8[2] = (_Float16)b0.z;  b8[3] = (_Float16)b0.w;
        b8[4] = (_Float16)b1v.x; b8[5] = (_Float16)b1v.y;
        b8[6] = (_Float16)b1v.z; b8[7] = (_Float16)b1v.w;
        #pragma unroll
        for (int m = 0; m < 4; ++m) {
            union { u16x8 raw; f16x8 v; } pu, qu;
            pu.raw = *(const u16x8*)&Ph[(long)ecol[m]*HD + kof];
            qu.raw = *(const u16x8*)&Qh[(long)erow[m]*HD + kof];
            const _Float16 d16 = (_Float16)edist[m];
            f16x8 s = pu.v + qu.v + b8 + d16 * c8;
            afr[m][kk] = __builtin_elementwise_max(s, z8);
        }
    }

    const f16x8* __restrict__ w2tv = (const f16x8*)w2t;
    f16x8 bfr[4];
    #pragma unroll
    for (int kk = 0; kk < 4; ++kk)
        bfr[kk] = w2tv[(0*16 + mr)*16 + kk*4 + qd];

    #pragma unroll 1
    for (int t = 0; t < 8; ++t) {
        f16x8 bnext[4];
        if (t < 7) {
            #pragma unroll
            for (int kk = 0; kk < 4; ++kk)
                bnext[kk] = w2tv[((t+1)*16 + mr)*16 + kk*4 + qd];
        }
        const int colg = t*16 + mr;
        const float bb = b2[colg];

        f32x4 acc[4];
        #pragma unroll
        for (int m = 0; m < 4; ++m) acc[m] = (f32x4){0.f, 0.f, 0.f, 0.f};
        #pragma unroll
        for (int kk = 0; kk < 4; ++kk)
            #pragma unroll
            for (int m = 0; m < 4; ++m)
                acc[m] = __builtin_amdgcn_mfma_f32_16x16x32_f16(afr[m][kk], bfr[kk], acc[m], 0, 0, 0);

        int rprev = -1;
        float run = 0.f;
        #pragma unroll
        for (int m = 0; m < 4; ++m) {
            #pragma unroll
            for (int r4 = 0; r4 < 4; ++r4) {
                const int rw = (int)rcv[m*4 + r4];
                const float v = fmaxf(acc[m][r4] + bb, 0.f);
                if (rw != rprev) {
                    if (rprev >= 0) atomAdd(&msum[(long)rprev*HD + colg], run);
                    rprev = rw; run = v;
                } else {
                    run += v;
                }
            }
        }
        atomAdd(&msum[(long)rprev*HD + colg], run);

        #pragma unroll
        for (int kk = 0; kk < 4; ++kk) bfr[kk] = bnext[kk];
    }
}

// ---------------- ligand-masked per-graph sum: batch-sorted run aggregation --------------
__global__ __launch_bounds__(256) void gsum_kernel(
    const unsigned short* __restrict__ xhi, const unsigned short* __restrict__ xlo,
    const int* __restrict__ batch,
    const int* __restrict__ ntype, float* __restrict__ gsum)
{
    const int tid = threadIdx.x;
    const int cg = tid & 31;          // float4 col group
    const int ns = tid >> 5;          // node strip 0..7
    const int n0 = blockIdx.x * 512 + ns * 64;

    int bprev = -1;
    float4 run = make_float4(0.f, 0.f, 0.f, 0.f);
    for (int i = 0; i < 64; ++i) {
        const int n = n0 + i;
        if (ntype[n] != 1) continue;
        const int b = batch[n];
        const ushort4 h  = *(const ushort4*)&xhi[(long)n*HD + cg*4];
        const ushort4 lo = *(const ushort4*)&xlo[(long)n*HD + cg*4];
        float4 v;
        v.x = bf2f(h.x) + bf2f(lo.x);
        v.y = bf2f(h.y) + bf2f(lo.y);
        v.z = bf2f(h.z) + bf2f(lo.z);
        v.w = bf2f(h.w) + bf2f(lo.w);
        if (b != bprev) {
            if (bprev >= 0) {
                float* dst = &gsum[bprev*HD + cg*4];
                atomAdd(dst+0, run.x); atomAdd(dst+1, run.y);
                atomAdd(dst+2, run.z); atomAdd(dst+3, run.w);
            }
            bprev = b; run = v;
        } else {
            run.x += v.x; run.y += v.y; run.z += v.z; run.w += v.w;
        }
    }
    if (bprev >= 0) {
        float* dst = &gsum[bprev*HD + cg*4];
        atomAdd(dst+0, run.x); atomAdd(dst+1, run.y);
        atomAdd(dst+2, run.z); atomAdd(dst+3, run.w);
    }
}

// ---------------- readout ----------------
__global__ __launch_bounds__(128) void readout_kernel(
    const float* __restrict__ gsum, const float* __restrict__ lcnt,
    const float* __restrict__ w1, const float* __restrict__ b1,
    const float* __restrict__ w2, const float* __restrict__ b2,
    float* __restrict__ out)
{
    __shared__ float gs[HD];
    __shared__ float red[2];
    const int b = blockIdx.x, j = threadIdx.x;
    gs[j] = gsum[b*HD + j] / fmaxf(lcnt[b], 1.f);
    __syncthreads();
    float acc = b1[j];
    for (int k = 0; k < HD; ++k) acc += gs[k]*w1[k*HD + j];
    float hg = fmaxf(acc, 0.f) * w2[j];
    #pragma unroll
    for (int off = 32; off > 0; off >>= 1) hg += __shfl_down(hg, off, 64);
    if ((j & 63) == 0) red[j >> 6] = hg;
    __syncthreads();
    if (j == 0) out[b] = red[0] + red[1] + b2[0];
}

extern "C" void kernel_launch(void* const* d_in, const int* in_sizes, int n_in,
                              void* d_out, int out_size, void* d_ws, size_t ws_size,
                              hipStream_t stream)
{
    const float* pos   = (const float*)d_in[0];
    const int*   z     = (const int*)d_in[1];
    const int*   batch = (const int*)d_in[2];
    const int*   eidx  = (const int*)d_in[3];
    const int*   ntype = (const int*)d_in[4];
    const float* emb   = (const float*)d_in[5];
    const float* lin_w = (const float*)d_in[6];
    const float* lin_b = (const float*)d_in[7];
    const float* mw1   = (const float*)d_in[8];
    const float* mb1   = (const float*)d_in[9];
    const float* mw2   = (const float*)d_in[10];
    const float* mb2   = (const float*)d_in[11];
    const float* uw    = (const float*)d_in[12];
    const float* ub    = (const float*)d_in[13];
    const float* rw1   = (const float*)d_in[14];
    const float* rb1   = (const float*)d_in[15];
    const float* rw2   = (const float*)d_in[16];
    const float* rb2   = (const float*)d_in[17];

    const int* row = eidx;
    const int* col = eidx + NE;

    float* ws     = (float*)d_ws;
    float* csum   = ws + O_CSUM;
    float* ccnt   = ws + O_CCNT;
    float* lcnt   = ws + O_LCNT;
    float* gsum   = ws + O_GSUM;
    int*   degi   = (int*)(ws + O_DEGI);
    float* posrel = ws + O_POSREL;
    unsigned int* rcS = (unsigned int*)(ws + O_RC);
    unsigned short* xhi = (unsigned short*)(ws + O_XHI);
    unsigned short* xlo = (unsigned short*)(ws + O_XLO);
    unsigned short* Ph  = (unsigned short*)(ws + O_P);
    unsigned short* Qh  = (unsigned short*)(ws + O_Q);
    float* msum   = ws + O_MSUM;
    unsigned short* w2t  = (unsigned short*)(ws + O_W2T);
    unsigned short* w1th = (unsigned short*)(ws + O_W1TH);
    unsigned short* w1tl = (unsigned short*)(ws + O_W1TL);
    unsigned short* wuth = (unsigned short*)(ws + O_WUTH);
    unsigned short* wutl = (unsigned short*)(ws + O_WUTL);
    int* chunkSum = (int*)(ws + O_CHK);
    int* rowStart = (int*)xhi;           // alias xhi head pre-lin_in
    int* cnt      = (int*)xhi + NN;

    (void)hipMemsetAsync(ws, 0, (size_t)(O_DEGI + NN) * sizeof(float), stream);
    (void)hipMemsetAsync(cnt, 0, (size_t)NN * sizeof(int), stream);

    stats_kernel  <<<NN/256, 256, 0, stream>>>(pos, batch, ntype, csum, ccnt, lcnt);
    deg_kernel    <<<NE/256, 256, 0, stream>>>(row, degi);
    posrel_kernel <<<NN/256, 256, 0, stream>>>(pos, batch, csum, ccnt, posrel);
    scanA_kernel  <<<256, 256, 0, stream>>>(degi, chunkSum);
    scanB_kernel  <<<1, 256, 0, stream>>>(chunkSum);
    scanC_kernel  <<<256, 256, 0, stream>>>(degi, chunkSum, rowStart);
    scatter_kernel<<<NE/256, 256, 0, stream>>>(row, col, rowStart, cnt, rcS);
    wprep_kernel  <<<384, 256, 0, stream>>>(mw1, uw, mw2, w1th, w1tl, wuth, wutl, w2t);

    lin_in_gemm<<<NN/32, 256, 0, stream>>>(emb, posrel, z, lin_w, lin_b, xhi, xlo);

    for (int l = 0; l < NL; ++l) {
        pq_gemm<<<NN/64, 256, 0, stream>>>(xhi, xlo, w1th + (size_t)l*32768, w1tl + (size_t)l*32768, Ph, Qh, msum);
        const float* W1 = mw1 + (size_t)l*257*HD;
        edge_msg_kernel<<<NE/256, 256, 0, stream>>>(Ph, Qh, posrel, rcS,
                                                    W1 + 256*HD, mb1 + l*HD,
                                                    w2t + (size_t)l*16384, mb2 + l*HD, msum);
        upd_gemm<<<NN/64, 256, 0, stream>>>(xhi, xlo, msum, degi,
                                            wuth + (size_t)l*32768, wutl + (size_t)l*32768,
                                            ub + l*HD);
    }

    gsum_kernel   <<<NN/512, 256, 0, stream>>>(xhi, xlo, batch, ntype, gsum);
    readout_kernel<<<NB, 128, 0, stream>>>(gsum, lcnt, rw1, rb1, rw2, rb2, (float*)d_out);
}